// Round 11
// baseline (477.997 us; speedup 1.0000x reference)
//
#include <hip/hip_runtime.h>

#define TT 1024
#define DD 2048
#define NH 16
#define NKV 4
#define HDIM 128
#define NE 8
#define NI 2048
#define EPSF 1e-5f
#define NP 4  // K-split partials for QKV / O-proj

typedef short bf16x8 __attribute__((ext_vector_type(8)));
typedef float f32x4 __attribute__((ext_vector_type(4)));

__device__ __forceinline__ unsigned short f2bf(float x) {
  unsigned u = __float_as_uint(x);
  u += 0x7FFFu + ((u >> 16) & 1u);
  return (unsigned short)(u >> 16);
}
__device__ __forceinline__ float bf2f(unsigned short h) {
  return __uint_as_float((unsigned)h << 16);
}
__device__ __forceinline__ void split2(float a, unsigned short& h,
                                       unsigned short& l) {
  h = f2bf(a);
  l = f2bf(a - bf2f(h));
}
// 30*tanh(v/30) via hw exp; ~1e-7 rel err (within split2 budget)
__device__ __forceinline__ float tanh_cap30(float v) {
  float e = __expf(v * (2.f / 30.f));
  return 30.f - 60.f / (e + 1.f);
}

__device__ __forceinline__ float wave_sum(float v) {
#pragma unroll
  for (int m = 32; m >= 1; m >>= 1) v += __shfl_xor(v, m, 64);
  return v;
}

__device__ __forceinline__ int swz4(int r) { return (r ^ (r >> 2)) & 3; }
__device__ __forceinline__ int swz8(int r) { return (r ^ (r >> 3)) & 7; }

// involutive chunk permutation within each 32-element k-group (producers of
// gll-consumed bf16 buffers write element k of row `row` at swzoff(row,k))
__device__ __forceinline__ int swzoff(int row, int k) {
  return (k & ~31) | ((((k >> 3) & 3) ^ swz4(row & 15)) << 3) | (k & 7);
}

// stage a [128 rows][32 k] pre-swizzled bf16 tile (8KB) via global_load_lds.
// chunk id == LDS slot: slot = (wid*2+j)*64 + lane  (rule #21 discipline)
__device__ __forceinline__ void stage_gll(const unsigned short* src, int ld,
                                          char* ldsbase, int wid, int lane) {
#pragma unroll
  for (int j = 0; j < 2; ++j) {
    int idx = (wid * 2 + j) * 64 + lane;  // chunk id 0..511
    int r = idx >> 2, c = idx & 3;
    const unsigned short* g = src + (long)r * ld + c * 8;
    __builtin_amdgcn_global_load_lds(
        (const __attribute__((address_space(1))) unsigned int*)g,
        (__attribute__((address_space(3))) unsigned int*)(ldsbase +
                                                         (wid * 2 + j) * 1024),
        16, 0, 0);
  }
}
__device__ __forceinline__ void ld_frag(const char* base, int wrow, int l15,
                                        int lg, bf16x8* dst) {
#pragma unroll
  for (int i = 0; i < 4; ++i) {
    int row = wrow + i * 16 + l15;
    dst[i] = *(const bf16x8*)(base + row * 64 + ((lg ^ swz4(row)) << 4));
  }
}
__device__ __forceinline__ void mm16(const bf16x8* xa, const bf16x8* xb,
                                     f32x4 (*acc)[4]) {
#pragma unroll
  for (int mi = 0; mi < 4; ++mi)
#pragma unroll
    for (int ni = 0; ni < 4; ++ni)
      acc[mi][ni] = __builtin_amdgcn_mfma_f32_16x16x32_bf16(
          xa[mi], xb[ni], acc[mi][ni], 0, 0, 0);
}

// ---------------------------------------------------------------------------
// 3-pass split-bf16 precise GEMM: C = A@B^T with A=Ah+Al, B^T rows = Bh+Bl.
// MODE 0: z = K-part index (k0 = z*Kh, C += z*czs), plain f32 store.
// MODE 1: z = head (QK^T): causal skip, tanh-cap, + per-tile softmax stats.
// MODE 2: z = head*8+chunk (PV): A-tile = exp(S - m)*inv staged on the fly
//         (softmax fused); causal 128-k chunks; C += chunk*czs + head*128.
// ---------------------------------------------------------------------------
template <int MODE>
__global__ __launch_bounds__(256) void pgemm3_k(
    const unsigned short* __restrict__ Ah, const unsigned short* __restrict__ Al,
    const unsigned short* __restrict__ Bh, const unsigned short* __restrict__ Bl,
    float* __restrict__ C, int Kh, int lda, int ldb, int ldc, long czs,
    float escale, float* __restrict__ SM, float* __restrict__ SS,
    const float* __restrict__ Sf) {
  int z = blockIdx.z;
  int m0 = blockIdx.y * 128, n0 = blockIdx.x * 128;
  int k0 = 0, kend = Kh;
  const float* Sbase = nullptr;
  int head = 0;
  if (MODE == 0) {
    k0 = z * Kh;
    kend = k0 + Kh;
    C += (long)z * czs;
  } else if (MODE == 1) {
    if (blockIdx.x > blockIdx.y) return;  // fully-masked causal tile
    Ah += (long)z * TT * lda;
    Al += (long)z * TT * lda;
    Bh += (long)(z >> 2) * TT * ldb;
    Bl += (long)(z >> 2) * TT * ldb;
    C += (long)z * czs;
  } else {
    head = z >> 3;
    int ch = z & 7;
    int limit = (blockIdx.y + 1) * 128;  // causal k limit for this q-block
    k0 = ch * 128;
    if (k0 >= limit) return;
    kend = k0 + 128;
    Sbase = Sf + (long)head * TT * TT;
    Bh += (long)(head >> 2) * HDIM * ldb;
    Bl += (long)(head >> 2) * HDIM * ldb;
    C += (long)ch * czs + head * HDIM;
  }

  __shared__ __align__(16) char lds[32768];
  __shared__ float mrow[128], invrow[128];
  int tid = threadIdx.x, lane = tid & 63, wid = tid >> 6;
  int wm = (wid >> 1) * 64, wn = (wid & 1) * 64;
  int l15 = lane & 15, lg = lane >> 4;

  if (MODE == 2) {
    // per-row softmax stats from fused QK tile-stats
    if (tid < 128) {
      int q = m0 + tid;
      int nt = blockIdx.y + 1;
      float m = -1e30f;
      for (int t = 0; t < nt; ++t)
        m = fmaxf(m, SM[((long)head * 8 + t) * TT + q]);
      float den = 0.f;
      for (int t = 0; t < nt; ++t) {
        long so = ((long)head * 8 + t) * TT + q;
        den += SS[so] * __expf(SM[so] - m);
      }
      mrow[tid] = m;
      invrow[tid] = 1.f / den;
    }
  }

  f32x4 acc[4][4];
#pragma unroll
  for (int i = 0; i < 4; ++i)
#pragma unroll
    for (int j = 0; j < 4; ++j) acc[i][j] = {0.f, 0.f, 0.f, 0.f};

  for (int kt = k0; kt < kend; kt += 32) {
    __syncthreads();
    if (MODE == 2) {
      // stage Ph/Pl tiles from S: p = exp(s - m) * inv (causal-masked)
#pragma unroll
      for (int j = 0; j < 2; ++j) {
        int idx = tid + j * 256;
        int r = idx >> 2, c = idx & 3;
        int q = m0 + r;
        const float* sp = Sbase + (long)q * TT + kt + c * 8;
        float4 s0 = *(const float4*)sp;
        float4 s1 = *(const float4*)(sp + 4);
        float mq = mrow[r], iq = invrow[r];
        bf16x8 ph, pl;
        int kg0 = kt + c * 8;
#pragma unroll
        for (int u = 0; u < 8; ++u) {
          float s = (u < 4) ? ((const float*)&s0)[u] : ((const float*)&s1)[u - 4];
          float p = (kg0 + u <= q) ? __expf(s - mq) * iq : 0.f;
          unsigned short hh, ll;
          split2(p, hh, ll);
          ((unsigned short*)&ph)[u] = hh;
          ((unsigned short*)&pl)[u] = ll;
        }
        int off = r * 64 + ((c ^ swz4(r)) << 4);
        *(bf16x8*)(lds + off) = ph;
        *(bf16x8*)(lds + 8192 + off) = pl;
      }
    } else {
      stage_gll(Ah + (long)m0 * lda + kt, lda, lds, wid, lane);
      stage_gll(Al + (long)m0 * lda + kt, lda, lds + 8192, wid, lane);
    }
    stage_gll(Bh + (long)n0 * ldb + kt, ldb, lds + 16384, wid, lane);
    stage_gll(Bl + (long)n0 * ldb + kt, ldb, lds + 24576, wid, lane);
    __syncthreads();
    bf16x8 fah[4], fal[4], fbh[4], fbl[4];
    ld_frag(lds, wm, l15, lg, fah);
    ld_frag(lds + 16384, wn, l15, lg, fbh);
    mm16(fah, fbh, acc);
    ld_frag(lds + 24576, wn, l15, lg, fbl);
    mm16(fah, fbl, acc);
    ld_frag(lds + 8192, wm, l15, lg, fal);
    mm16(fal, fbh, acc);
  }

  if (MODE == 1) {
    int bx = blockIdx.x;
    bool diag = (bx == blockIdx.y);
    float vcap[4][4][4];
#pragma unroll
    for (int mi = 0; mi < 4; ++mi)
#pragma unroll
      for (int ni = 0; ni < 4; ++ni)
#pragma unroll
        for (int rr = 0; rr < 4; ++rr)
          vcap[mi][ni][rr] = tanh_cap30(acc[mi][ni][rr] * escale);
#pragma unroll
    for (int mi = 0; mi < 4; ++mi)
#pragma unroll
      for (int ni = 0; ni < 4; ++ni)
#pragma unroll
        for (int rr = 0; rr < 4; ++rr) {
          int ml = m0 + wm + mi * 16 + lg * 4 + rr;
          int col = n0 + wn + ni * 16 + l15;
          C[(long)ml * ldc + col] = vcap[mi][ni][rr];
        }
    __syncthreads();  // reuse lds for stats reduction
    float* wmx = (float*)lds;           // [2][128]
    float* wsm = (float*)(lds + 1024);  // [2][128]
    int ch = wid & 1;
#pragma unroll
    for (int mi = 0; mi < 4; ++mi)
#pragma unroll
      for (int rr = 0; rr < 4; ++rr) {
        int wr = wm + mi * 16 + lg * 4 + rr;
        int rowg = m0 + wr;
        float mx = -1e30f;
#pragma unroll
        for (int ni = 0; ni < 4; ++ni) {
          int colg = n0 + wn + ni * 16 + l15;
          if (!diag || colg <= rowg) mx = fmaxf(mx, vcap[mi][ni][rr]);
        }
#pragma unroll
        for (int mk = 1; mk <= 8; mk <<= 1)
          mx = fmaxf(mx, __shfl_xor(mx, mk, 64));
        if (l15 == 0) wmx[ch * 128 + wr] = mx;
      }
    __syncthreads();
#pragma unroll
    for (int mi = 0; mi < 4; ++mi)
#pragma unroll
      for (int rr = 0; rr < 4; ++rr) {
        int wr = wm + mi * 16 + lg * 4 + rr;
        int rowg = m0 + wr;
        float m2 = fmaxf(wmx[wr], wmx[128 + wr]);
        float s = 0.f;
#pragma unroll
        for (int ni = 0; ni < 4; ++ni) {
          int colg = n0 + wn + ni * 16 + l15;
          if (!diag || colg <= rowg) s += __expf(vcap[mi][ni][rr] - m2);
        }
#pragma unroll
        for (int mk = 1; mk <= 8; mk <<= 1) s += __shfl_xor(s, mk, 64);
        if (l15 == 0) wsm[ch * 128 + wr] = s;
      }
    __syncthreads();
    if (tid < 128) {
      float m2 = fmaxf(wmx[tid], wmx[128 + tid]);
      float s = wsm[tid] + wsm[128 + tid];
      long so = ((long)z * 8 + bx) * TT + m0 + tid;
      SM[so] = m2;
      SS[so] = s;
    }
    return;
  }

#pragma unroll
  for (int mi = 0; mi < 4; ++mi)
#pragma unroll
    for (int ni = 0; ni < 4; ++ni)
#pragma unroll
      for (int rr = 0; rr < 4; ++rr) {
        int ml = m0 + wm + mi * 16 + lg * 4 + rr;
        int col = n0 + wn + ni * 16 + l15;
        C[(long)ml * ldc + col] = acc[mi][ni][rr];
      }
}

// ---------------------------------------------------------------------------
// MoE bf16 GEMM: 128x128 tile, 256 threads, K-split 2^KSL, gll A.
// z = expert<<KSL | kp. C = A[M][K](bf16 linear) @ B[K][N](f32, cast on stage)
// be computed in-kernel from cnt prefix (no scan dispatch).
// AMODE 1: A row gathered via tok; AMODE 2: A row = base+m (compact)
// EP 0: bf16 partial store at compacted rows (+ kp*pzs)
// EP 3: weighted bf16 scatter into slots_out (+ kp*pzs)
// ---------------------------------------------------------------------------
template <int AMODE, int EP, int KSL>
__global__ __launch_bounds__(256) void gemm_k(
    const unsigned short* __restrict__ A, const float* __restrict__ Bf,
    unsigned short* __restrict__ Cb, int N, int K, int lda, int ldb, int ldc,
    long bzs, long pzs, const int* __restrict__ cnt,
    const int* __restrict__ tok, const int* __restrict__ slotp,
    const float* __restrict__ wtp, unsigned short* __restrict__ slots_out) {
  int z = blockIdx.z;
  int e = z >> KSL, kp = z & ((1 << KSL) - 1);
  Bf += (long)e * bzs;
  int Me = cnt[e];
  int be = 0;
  for (int q = 0; q < e; ++q) be += cnt[q];
  int m0 = blockIdx.y * 128, n0 = blockIdx.x * 128;
  if (m0 >= Me) return;
  int Kc = K >> KSL, kbeg = kp * Kc, klim = kbeg + Kc;

  __shared__ __align__(16) char lds[32768];
  const int BOFF = 16384;
  int tid = threadIdx.x, lane = tid & 63, wid = tid >> 6;
  int wm = (wid >> 1) * 64, wn = (wid & 1) * 64;
  int l15 = lane & 15, lg = lane >> 4;

  f32x4 acc[4][4];
#pragma unroll
  for (int i = 0; i < 4; ++i)
#pragma unroll
    for (int j = 0; j < 4; ++j) acc[i][j] = {0.f, 0.f, 0.f, 0.f};

  for (int kt = kbeg; kt < klim; kt += 64) {
    __syncthreads();
    // A tile [128][64] bf16 via gll: linear LDS dest + XOR-swizzled source.
    // chunk id MUST equal LDS slot = (wid*4+i)*64 + lane (rule #21).
#pragma unroll
    for (int i = 0; i < 4; ++i) {
      int idx = (wid * 4 + i) * 64 + lane;  // chunk id 0..1023 == slot
      int r = idx >> 3, c = idx & 7;
      int gm = m0 + r;
      long arow;
      if (AMODE == 1)
        arow = (gm < Me) ? (long)tok[e * TT + gm] : 0;
      else
        arow = (long)be + gm;
      int cs = c ^ swz8(r);
      const unsigned short* g = A + arow * (long)lda + kt + cs * 8;
      __builtin_amdgcn_global_load_lds(
          (const __attribute__((address_space(1))) unsigned int*)g,
          (__attribute__((address_space(3))) unsigned int*)(lds +
                                                           (wid * 4 + i) * 1024),
          16, 0, 0);
    }
    // B tile as [128 n][64 k]: coalesced column loads -> pack -> b128 write
#pragma unroll
    for (int i = 0; i < 4; ++i) {
      int gidx = tid + i * 256;
      int n = gidx & 127, kc = gidx >> 7;
      const float* src = Bf + (long)(kt + kc * 8) * ldb + n0 + n;
      bf16x8 v;
#pragma unroll
      for (int u = 0; u < 8; ++u)
        ((unsigned short*)&v)[u] = f2bf(src[(long)u * ldb]);
      *(bf16x8*)(lds + BOFF + n * 128 + ((kc ^ swz8(n)) << 4)) = v;
    }
    __syncthreads();
#pragma unroll
    for (int s = 0; s < 2; ++s) {
      bf16x8 af[4], bfr[4];
      int slotk = s * 4 + lg;
#pragma unroll
      for (int mi = 0; mi < 4; ++mi) {
        int row = wm + mi * 16 + l15;
        af[mi] =
            *(const bf16x8*)(lds + row * 128 + ((slotk ^ swz8(row)) << 4));
      }
#pragma unroll
      for (int ni = 0; ni < 4; ++ni) {
        int row = wn + ni * 16 + l15;
        bfr[ni] = *(const bf16x8*)(lds + BOFF + row * 128 +
                                   ((slotk ^ swz8(row)) << 4));
      }
      mm16(af, bfr, acc);
    }
  }
#pragma unroll
  for (int mi = 0; mi < 4; ++mi)
#pragma unroll
    for (int ni = 0; ni < 4; ++ni)
#pragma unroll
      for (int rr = 0; rr < 4; ++rr) {
        int ml = m0 + wm + mi * 16 + lg * 4 + rr;
        int col = n0 + wn + ni * 16 + l15;
        float val = acc[mi][ni][rr];
        if (ml < Me) {
          if (EP == 0) {
            Cb[(long)kp * pzs + (long)(be + ml) * ldc + col] = f2bf(val);
          } else {
            int t = tok[e * TT + ml];
            int s = slotp[e * TT + ml];
            float w = wtp[e * TT + ml];
            slots_out[(long)kp * pzs + ((long)s * TT + t) * DD + col] =
                f2bf(val * w);
          }
        }
      }
}

// ---------------------------------------------------------------------------
// prep: blocks [0,2560) = transpose+split of both attention weights
//       (pre-swizzled); blocks [2560, 2560+TT) = pre-attn rmsnorm+split2.
//       block 0 also zeroes cnt.
__global__ __launch_bounds__(256) void prep_k(
    const float* __restrict__ Wq, unsigned short* __restrict__ Thq,
    unsigned short* __restrict__ Tlq, const float* __restrict__ Wo,
    unsigned short* __restrict__ Tho, unsigned short* __restrict__ Tlo,
    const float* __restrict__ x, const float* __restrict__ wpre,
    unsigned short* __restrict__ h1h, unsigned short* __restrict__ h1l,
    int* __restrict__ cnt) {
  __shared__ float lds[64 * 65];
  int b = blockIdx.x, tid = threadIdx.x;
  if (b == 0 && tid < NE) cnt[tid] = 0;
  if (b >= 2560) {  // ---- rmsnorm path ----
    int t = b - 2560;
    const float* xr = x + (long)t * DD;
    float xv[8];
    float ss = 0.f;
#pragma unroll
    for (int i = 0; i < 8; ++i) {
      float v = xr[tid + i * 256];
      xv[i] = v;
      ss += v * v;
    }
    ss = wave_sum(ss);
    if ((tid & 63) == 0) lds[tid >> 6] = ss;
    __syncthreads();
    float r = rsqrtf((lds[0] + lds[1] + lds[2] + lds[3]) * (1.f / DD) + EPSF);
#pragma unroll
    for (int i = 0; i < 8; ++i) {
      int d = tid + i * 256;
      int ds = swzoff(t, d);
      split2(xv[i] * r * wpre[d], h1h[(long)t * DD + ds],
             h1l[(long)t * DD + ds]);
    }
    return;
  }
  // ---- weight transpose+split path ----
  const float* W;
  unsigned short *Th, *Tl;
  int K = DD, N, bx, by;
  if (b < 1536) {  // w_qkv: [2048][3072]
    W = Wq; Th = Thq; Tl = Tlq; N = 3072; bx = b % 48; by = b / 48;
  } else {  // w_o: [2048][2048]
    int b2 = b - 1536;
    W = Wo; Th = Tho; Tl = Tlo; N = DD; bx = b2 % 32; by = b2 / 32;
  }
  int n0 = bx * 64, k0 = by * 64;
#pragma unroll
  for (int i = 0; i < 4; ++i) {
    int idx = tid + i * 256;  // 1024 float4s = 64k x 64n
    int kr = idx >> 4, cg = idx & 15;
    float4 v = *(const float4*)(W + (long)(k0 + kr) * N + n0 + cg * 4);
    float* p = &lds[kr * 65 + cg * 4];
    p[0] = v.x; p[1] = v.y; p[2] = v.z; p[3] = v.w;
  }
  __syncthreads();
#pragma unroll
  for (int i = 0; i < 2; ++i) {
    int idx = tid + i * 256;  // 512 out-chunks of 8 k
    int n = idx >> 3, kc = idx & 7;
    bf16x8 h8, l8;
#pragma unroll
    for (int u = 0; u < 8; ++u) {
      unsigned short hh, ll;
      split2(lds[(kc * 8 + u) * 65 + n], hh, ll);
      ((unsigned short*)&h8)[u] = hh;
      ((unsigned short*)&l8)[u] = ll;
    }
    int row = n0 + n;
    long o = (long)row * K + swzoff(row, k0 + kc * 8);
    *(bf16x8*)(Th + o) = h8;
    *(bf16x8*)(Tl + o) = l8;
  }
}

// fused: blocks 0..TT-1 = q/k RoPE+split2; blocks TT.. = V transpose+split2
__global__ __launch_bounds__(256) void ropevt_k(
    const int* __restrict__ pos, const float* __restrict__ qp,
    unsigned short* __restrict__ qh, unsigned short* __restrict__ ql,
    unsigned short* __restrict__ kh, unsigned short* __restrict__ kl,
    unsigned short* __restrict__ Vh, unsigned short* __restrict__ Vl) {
  __shared__ __align__(16) float smem[64 * 129];
  int b = blockIdx.x, tid = threadIdx.x;
  const long PS = (long)TT * 3072;
  if (b < TT) {  // ---- RoPE on q,k ----
    float* cs = smem;
    float* sn = smem + 64;
    int t = b;
    float pf = (float)pos[t];
    if (tid < 64) {
      float inv = exp2f(-(float)tid * 0.20762050593046015f);  // log2(1e4)/64
      float f = pf * inv;
      cs[tid] = cosf(f);
      sn[tid] = sinf(f);
    }
    __syncthreads();
    const float* row = qp + (long)t * 3072;
#pragma unroll
    for (int i = 0; i < 4; ++i) {
      int idx = tid + i * 256;  // q: 16 heads x 64
      int h = idx >> 6, j = idx & 63;
      float x1 = 0.f, x2 = 0.f;
#pragma unroll
      for (int p = 0; p < NP; ++p) {
        x1 += row[p * PS + h * HDIM + j];
        x2 += row[p * PS + h * HDIM + 64 + j];
      }
      float c = cs[j], s = sn[j];
      long base = ((long)h * TT + t) * HDIM;
      split2(x1 * c - x2 * s, qh[base + swzoff(t, j)], ql[base + swzoff(t, j)]);
      split2(x2 * c + x1 * s, qh[base + swzoff(t, 64 + j)],
             ql[base + swzoff(t, 64 + j)]);
    }
    {
      int k2 = tid >> 6, j = tid & 63;  // k: 4 heads x 64
      float x1 = 0.f, x2 = 0.f;
#pragma unroll
      for (int p = 0; p < NP; ++p) {
        x1 += row[p * PS + 2048 + k2 * HDIM + j];
        x2 += row[p * PS + 2048 + k2 * HDIM + 64 + j];
      }
      float c = cs[j], s = sn[j];
      long base = ((long)k2 * TT + t) * HDIM;
      split2(x1 * c - x2 * s, kh[base + swzoff(t, j)], kl[base + swzoff(t, j)]);
      split2(x2 * c + x1 * s, kh[base + swzoff(t, 64 + j)],
             kl[base + swzoff(t, 64 + j)]);
    }
  } else {  // ---- V transpose ----
    int bb = b - TT;
    int tb = bb & 7, kv = bb >> 3;
    int t0 = tb * 128;
#pragma unroll
    for (int dh = 0; dh < 2; ++dh) {
      if (dh) __syncthreads();
#pragma unroll
      for (int i = 0; i < 8; ++i) {
        int fidx = tid + i * 256;  // 2048 float4s = 128t x 64d
        int t = fidx >> 4, dq = fidx & 15;
        long gi = (long)(t0 + t) * 3072 + 2560 + kv * HDIM + dh * 64 + dq * 4;
        float4 a = *(const float4*)(qp + gi);
#pragma unroll
        for (int p = 1; p < NP; ++p) {
          float4 bb4 = *(const float4*)(qp + p * PS + gi);
          a.x += bb4.x; a.y += bb4.y; a.z += bb4.z; a.w += bb4.w;
        }
        smem[(dq * 4 + 0) * 129 + t] = a.x;
        smem[(dq * 4 + 1) * 129 + t] = a.y;
        smem[(dq * 4 + 2) * 129 + t] = a.z;
        smem[(dq * 4 + 3) * 129 + t] = a.w;
      }
      __syncthreads();
#pragma unroll
      for (int i = 0; i < 4; ++i) {
        int cidx = tid + i * 256;  // 1024 chunks = 64d x 16tc
        int d = cidx >> 4, tc = cidx & 15;
        bf16x8 h8, l8;
#pragma unroll
        for (int u = 0; u < 8; ++u) {
          unsigned short hh, ll;
          split2(smem[d * 129 + tc * 8 + u], hh, ll);
          ((unsigned short*)&h8)[u] = hh;
          ((unsigned short*)&l8)[u] = ll;
        }
        int rowd = dh * 64 + d;
        long o = ((long)kv * HDIM + rowd) * TT + swzoff(rowd, t0 + tc * 8);
        *(bf16x8*)(Vh + o) = h8;
        *(bf16x8*)(Vl + o) = l8;
      }
    }
  }
}

// sum valid PV chunks, split2 -> ob (pre-swizzled)
__global__ __launch_bounds__(256) void obreduce_k(const float* __restrict__ obp,
                                                  unsigned short* __restrict__ oh,
                                                  unsigned short* __restrict__ ol) {
  int m = blockIdx.x, tid = threadIdx.x;
  int nv = (m >> 7) + 1;  // 128-k chunks with k0 <= m
#pragma unroll
  for (int i = 0; i < 8; ++i) {
    int d = tid + i * 256;
    float s = 0.f;
    for (int c = 0; c < nv; ++c) s += obp[(long)c * TT * DD + (long)m * DD + d];
    int ds = swzoff(m, d);
    split2(s, oh[(long)m * DD + ds], ol[(long)m * DD + ds]);
  }
}

// post-attn residual + two rmsnorms + h2 bf16 + FUSED gate top-2 routing
__global__ __launch_bounds__(256) void post_attn_gate_k(
    const float* __restrict__ ap, const float* __restrict__ hidden,
    const float* __restrict__ w_post, const float* __restrict__ w_pre2,
    const float* __restrict__ wg, float* __restrict__ resid1,
    unsigned short* __restrict__ h2b, int* cnt, int* tok, int* slotp,
    float* wtp) {
  __shared__ float red[4];
  __shared__ float red8[4][8];
  int t = blockIdx.x, tid = threadIdx.x;
  const long PS = (long)TT * DD;
  float av[8];
  float ss = 0.f;
#pragma unroll
  for (int i = 0; i < 8; ++i) {
    long o = (long)t * DD + tid + i * 256;
    float v = 0.f;
#pragma unroll
    for (int p = 0; p < NP; ++p) v += ap[p * PS + o];
    av[i] = v;
    ss += v * v;
  }
  ss = wave_sum(ss);
  if ((tid & 63) == 0) red[tid >> 6] = ss;
  __syncthreads();
  float r1 = rsqrtf((red[0] + red[1] + red[2] + red[3]) * (1.f / DD) + EPSF);
  __syncthreads();
  float rv[8];
  float ss2 = 0.f;
#pragma unroll
  for (int i = 0; i < 8; ++i) {
    int d = tid + i * 256;
    float v = hidden[(long)t * DD + d] + av[i] * r1 * w_post[d];
    rv[i] = v;
    resid1[(long)t * DD + d] = v;
    ss2 += v * v;
  }
  ss2 = wave_sum(ss2);
  if ((tid & 63) == 0) red[tid >> 6] = ss2;
  __syncthreads();
  float r2 = rsqrtf((red[0] + red[1] + red[2] + red[3]) * (1.f / DD) + EPSF);
  float a[8] = {0, 0, 0, 0, 0, 0, 0, 0};
#pragma unroll
  for (int i = 0; i < 8; ++i) {
    int d = tid + i * 256;
    float hv = rv[i] * r2 * w_pre2[d];
    h2b[(long)t * DD + d] = f2bf(hv);  // linear (MoE gll source-swizzles)
    const float* wr = wg + d * 8;
#pragma unroll
    for (int e = 0; e < 8; ++e) a[e] += hv * wr[e];
  }
#pragma unroll
  for (int e = 0; e < 8; ++e) a[e] = wave_sum(a[e]);
  if ((tid & 63) == 0) {
#pragma unroll
    for (int e = 0; e < 8; ++e) red8[tid >> 6][e] = a[e];
  }
  __syncthreads();
  if (tid == 0) {
    float l[8], p[8];
    float m = -1e30f;
    for (int e = 0; e < 8; ++e) {
      float v = red8[0][e] + red8[1][e] + red8[2][e] + red8[3][e];
      v = 30.f * tanhf(v * (1.f / 30.f));  // exact: top-2 flip-sensitive
      l[e] = v;
      m = fmaxf(m, v);
    }
    float s = 0.f;
    for (int e = 0; e < 8; ++e) { p[e] = expf(l[e] - m); s += p[e]; }
    for (int e = 0; e < 8; ++e) p[e] /= s;
    int i1 = 0;
    for (int e = 1; e < 8; ++e) if (p[e] > p[i1]) i1 = e;
    int i2 = (i1 == 0) ? 1 : 0;
    for (int e = 0; e < 8; ++e) if (e != i1 && p[e] > p[i2]) i2 = e;
    int q1 = atomicAdd(&cnt[i1], 1);
    tok[i1 * TT + q1] = t; slotp[i1 * TT + q1] = 0; wtp[i1 * TT + q1] = p[i1];
    int q2 = atomicAdd(&cnt[i2], 1);
    tok[i2 * TT + q2] = t; slotp[i2 * TT + q2] = 1; wtp[i2 * TT + q2] = p[i2];
  }
}

// act over sum of 4 bf16 K-split gu partials (fast gelu)
__global__ __launch_bounds__(256) void act_k(const unsigned short* __restrict__ gu,
                                             unsigned short* __restrict__ actb) {
  long a = blockIdx.x;
  const long PS = (long)2 * TT * 2 * NI;
  const unsigned short* g0 = gu + a * (2 * NI);
  for (int i = threadIdx.x; i < NI; i += 256) {
    float gg = 0.f, uu = 0.f;
#pragma unroll
    for (int p = 0; p < 4; ++p) {
      gg += bf2f(g0[p * PS + i]);
      uu += bf2f(g0[p * PS + i + NI]);
    }
    float y = 0.7978845608028654f * (gg + 0.044715f * gg * gg * gg);
    float ey = __expf(2.f * y);
    float th = 1.f - 2.f / (ey + 1.f);
    actb[a * NI + i] = f2bf(0.5f * gg * (1.f + th) * uu);
  }
}

// final: sum 8 bf16 slot planes (4 kp x 2 slots) + rmsnorm + resid
__global__ __launch_bounds__(256) void final_k(
    const float* __restrict__ resid1, const unsigned short* __restrict__ slots,
    const float* __restrict__ w2, float* __restrict__ out) {
  __shared__ float red[4];
  int t = blockIdx.x, tid = threadIdx.x;
  const long PL = (long)TT * DD;
  float mv[8];
  float ss = 0.f;
#pragma unroll
  for (int i = 0; i < 8; ++i) {
    long o = (long)t * DD + tid + i * 256;
    float v = 0.f;
#pragma unroll
    for (int p = 0; p < 8; ++p) v += bf2f(slots[p * PL + o]);
    mv[i] = v;
    ss += v * v;
  }
  ss = wave_sum(ss);
  if ((tid & 63) == 0) red[tid >> 6] = ss;
  __syncthreads();
  float r = rsqrtf((red[0] + red[1] + red[2] + red[3]) * (1.f / DD) + EPSF);
#pragma unroll
  for (int i = 0; i < 8; ++i) {
    int d = tid + i * 256;
    out[(long)t * DD + d] = resid1[(long)t * DD + d] + mv[i] * r * w2[d];
  }
}

__global__ void sentinel_k(float* out) { out[threadIdx.x] = 12345.0f; }

// ---------------------------------------------------------------------------
extern "C" void kernel_launch(void* const* d_in, const int* in_sizes, int n_in,
                              void* d_out, int out_size, void* d_ws,
                              size_t ws_size, hipStream_t stream) {
  const int* pos = (const int*)d_in[0];
  const float* hidden = (const float*)d_in[1];
  const float* w_qkv = (const float*)d_in[2];
  const float* w_o = (const float*)d_in[3];
  const float* w_gate = (const float*)d_in[4];
  const float* w_gu = (const float*)d_in[5];
  const float* w_down = (const float*)d_in[6];
  const float* w_pre_attn = (const float*)d_in[7];
  const float* w_post_attn = (const float*)d_in[8];
  const float* w_pre_moe = (const float*)d_in[9];
  const float* w_post_moe = (const float*)d_in[10];
  float* out = (float*)d_out;

  char* ws = (char*)d_ws;
  size_t off = 0;
  auto alloc = [&](size_t bytes) {
    char* p = ws + off;
    off += (bytes + 255) & ~(size_t)255;
    return p;
  };
  typedef unsigned short u16;
  u16* h1h = (u16*)alloc((size_t)TT * DD * 2);
  u16* h1l = (u16*)alloc((size_t)TT * DD * 2);
  u16* wqkvTh = (u16*)alloc((size_t)3072 * DD * 2);
  u16* wqkvTl = (u16*)alloc((size_t)3072 * DD * 2);
  float* qkvp = (float*)alloc((size_t)NP * TT * 3072 * 4);
  u16* qh_ = (u16*)alloc((size_t)NH * TT * HDIM * 2);
  u16* ql_ = (u16*)alloc((size_t)NH * TT * HDIM * 2);
  u16* kh_ = (u16*)alloc((size_t)NKV * TT * HDIM * 2);
  u16* kl_ = (u16*)alloc((size_t)NKV * TT * HDIM * 2);
  u16* vth = (u16*)alloc((size_t)NKV * HDIM * TT * 2);
  u16* vtl = (u16*)alloc((size_t)NKV * HDIM * TT * 2);
  float* S = (float*)alloc((size_t)NH * TT * TT * 4);
  float* SMb = (float*)alloc((size_t)NH * 8 * TT * 4);
  float* SSb = (float*)alloc((size_t)NH * 8 * TT * 4);
  float* obp = (float*)alloc((size_t)8 * TT * DD * 4);
  u16* obh = (u16*)alloc((size_t)TT * DD * 2);
  u16* obl = (u16*)alloc((size_t)TT * DD * 2);
  u16* woTh = (u16*)alloc((size_t)DD * DD * 2);
  u16* woTl = (u16*)alloc((size_t)DD * DD * 2);
  float* attnp = (float*)alloc((size_t)NP * TT * DD * 4);
  float* resid1 = (float*)alloc((size_t)TT * DD * 4);
  u16* h2b = (u16*)alloc((size_t)TT * DD * 2);
  int* cnt = (int*)alloc(NE * 4);
  int* tok = (int*)alloc((size_t)NE * TT * 4);
  int* slotp = (int*)alloc((size_t)NE * TT * 4);
  float* wtp = (float*)alloc((size_t)NE * TT * 4);
  u16* gu = (u16*)alloc((size_t)4 * 2 * TT * 2 * NI * 2);  // [kp4][2TT][2NI]
  u16* actb = (u16*)alloc((size_t)2 * TT * NI * 2);
  u16* slots = (u16*)alloc((size_t)4 * 2 * TT * DD * 2);   // [kp4][2][TT][DD]

  if (off > ws_size) {  // distinctive failure signal, no OOB writes
    sentinel_k<<<1, 256, 0, stream>>>(out);
    return;
  }

  dim3 blk(256);

  // weights transpose+split + pre-attn rmsnorm + cnt zeroing (one dispatch)
  prep_k<<<2560 + TT, blk, 0, stream>>>(w_qkv, wqkvTh, wqkvTl, w_o, woTh,
                                        woTl, hidden, w_pre_attn, h1h, h1l,
                                        cnt);

  // qkv partials (K split in NP)
  pgemm3_k<0><<<dim3(3072 / 128, TT / 128, NP), blk, 0, stream>>>(
      h1h, h1l, wqkvTh, wqkvTl, qkvp, DD / NP, DD, DD, 3072, (long)TT * 3072,
      0.f, nullptr, nullptr, nullptr);

  ropevt_k<<<TT + 32, blk, 0, stream>>>(pos, qkvp, qh_, ql_, kh_, kl_, vth,
                                        vtl);

  // S = cap_tanh(scale * Q K^T), causal skip, + fused softmax tile-stats
  pgemm3_k<1><<<dim3(TT / 128, TT / 128, NH), blk, 0, stream>>>(
      qh_, ql_, kh_, kl_, S, HDIM, HDIM, HDIM, TT, (long)TT * TT,
      0.08838834764831845f, SMb, SSb, nullptr);

  // O partials: softmax fused into PV A-staging; 128-k causal chunks
  pgemm3_k<2><<<dim3(1, TT / 128, NH * 8), blk, 0, stream>>>(
      nullptr, nullptr, vth, vtl, obp, 128, TT, TT, DD, (long)TT * DD, 0.f,
      SMb, SSb, S);
  obreduce_k<<<TT, blk, 0, stream>>>(obp, obh, obl);

  // attn partials = O @ w_o (K split in NP)
  pgemm3_k<0><<<dim3(DD / 128, TT / 128, NP), blk, 0, stream>>>(
      obh, obl, woTh, woTl, attnp, DD / NP, DD, DD, DD, (long)TT * DD, 0.f,
      nullptr, nullptr, nullptr);

  post_attn_gate_k<<<TT, blk, 0, stream>>>(attnp, hidden, w_post_attn,
                                           w_pre_moe, w_gate, resid1, h2b, cnt,
                                           tok, slotp, wtp);

  // gu partials [4][2TT][2NI] bf16 = h2[tok] @ w_gate_up[e]  (K-split 4)
  gemm_k<1, 0, 2><<<dim3(2 * NI / 128, TT / 128, NE * 4), blk, 0, stream>>>(
      h2b, w_gu, gu, 2 * NI, DD, DD, 2 * NI, 2 * NI, (long)DD * 2 * NI,
      (long)2 * TT * 2 * NI, cnt, tok, nullptr, nullptr, nullptr);

  act_k<<<2 * TT, blk, 0, stream>>>(gu, actb);

  // down partials -> slots [4][2][TT][DD] bf16  (K-split 4)
  gemm_k<2, 3, 2><<<dim3(DD / 128, TT / 128, NE * 4), blk, 0, stream>>>(
      actb, w_down, nullptr, DD, NI, NI, DD, DD, (long)NI * DD,
      (long)2 * TT * DD, cnt, tok, slotp, wtp, slots);

  final_k<<<TT, blk, 0, stream>>>(resid1, slots, w_post_moe, out);
}

// Round 12
// 446.682 us; speedup vs baseline: 1.0701x; 1.0701x over previous
//
#include <hip/hip_runtime.h>

#define TT 1024
#define DD 2048
#define NH 16
#define NKV 4
#define HDIM 128
#define NE 8
#define NI 2048
#define EPSF 1e-5f
#define NP 4  // K-split partials for QKV / O-proj

typedef short bf16x8 __attribute__((ext_vector_type(8)));
typedef float f32x4 __attribute__((ext_vector_type(4)));

__device__ __forceinline__ unsigned short f2bf(float x) {
  unsigned u = __float_as_uint(x);
  u += 0x7FFFu + ((u >> 16) & 1u);
  return (unsigned short)(u >> 16);
}
__device__ __forceinline__ float bf2f(unsigned short h) {
  return __uint_as_float((unsigned)h << 16);
}
__device__ __forceinline__ void split2(float a, unsigned short& h,
                                       unsigned short& l) {
  h = f2bf(a);
  l = f2bf(a - bf2f(h));
}
// 30*tanh(v/30) via hw exp; ~1e-7 rel err (within split2 budget)
__device__ __forceinline__ float tanh_cap30(float v) {
  float e = __expf(v * (2.f / 30.f));
  return 30.f - 60.f / (e + 1.f);
}

__device__ __forceinline__ float wave_sum(float v) {
#pragma unroll
  for (int m = 32; m >= 1; m >>= 1) v += __shfl_xor(v, m, 64);
  return v;
}

__device__ __forceinline__ int swz4(int r) { return (r ^ (r >> 2)) & 3; }
__device__ __forceinline__ int swz8(int r) { return (r ^ (r >> 3)) & 7; }

// involutive chunk permutation within each 32-element k-group (producers of
// gll-consumed bf16 buffers write element k of row `row` at swzoff(row,k))
__device__ __forceinline__ int swzoff(int row, int k) {
  return (k & ~31) | ((((k >> 3) & 3) ^ swz4(row & 15)) << 3) | (k & 7);
}

// stage a [128 rows][32 k] pre-swizzled bf16 tile (8KB) via global_load_lds.
// chunk id == LDS slot: slot = (wid*2+j)*64 + lane  (rule #21 discipline)
__device__ __forceinline__ void stage_gll(const unsigned short* src, int ld,
                                          char* ldsbase, int wid, int lane) {
#pragma unroll
  for (int j = 0; j < 2; ++j) {
    int idx = (wid * 2 + j) * 64 + lane;  // chunk id 0..511
    int r = idx >> 2, c = idx & 3;
    const unsigned short* g = src + (long)r * ld + c * 8;
    __builtin_amdgcn_global_load_lds(
        (const __attribute__((address_space(1))) unsigned int*)g,
        (__attribute__((address_space(3))) unsigned int*)(ldsbase +
                                                         (wid * 2 + j) * 1024),
        16, 0, 0);
  }
}
__device__ __forceinline__ void ld_frag(const char* base, int wrow, int l15,
                                        int lg, bf16x8* dst) {
#pragma unroll
  for (int i = 0; i < 4; ++i) {
    int row = wrow + i * 16 + l15;
    dst[i] = *(const bf16x8*)(base + row * 64 + ((lg ^ swz4(row)) << 4));
  }
}
__device__ __forceinline__ void mm16(const bf16x8* xa, const bf16x8* xb,
                                     f32x4 (*acc)[4]) {
#pragma unroll
  for (int mi = 0; mi < 4; ++mi)
#pragma unroll
    for (int ni = 0; ni < 4; ++ni)
      acc[mi][ni] = __builtin_amdgcn_mfma_f32_16x16x32_bf16(
          xa[mi], xb[ni], acc[mi][ni], 0, 0, 0);
}

// ---------------------------------------------------------------------------
// 3-pass split-bf16 precise GEMM: C = A@B^T with A=Ah+Al, B^T rows = Bh+Bl.
// MODE 0: z = K-part index (k0 = z*Kh, C += z*czs), plain f32 store.
// MODE 1: z = head (QK^T): causal skip, tanh-cap, + per-tile softmax stats.
// MODE 2: z = head*8+chunk (PV): A-tile = exp(S - m)*inv staged on the fly
//         (softmax fused); causal 128-k chunks; C += chunk*czs + head*128.
// ---------------------------------------------------------------------------
template <int MODE>
__global__ __launch_bounds__(256) void pgemm3_k(
    const unsigned short* __restrict__ Ah, const unsigned short* __restrict__ Al,
    const unsigned short* __restrict__ Bh, const unsigned short* __restrict__ Bl,
    float* __restrict__ C, int Kh, int lda, int ldb, int ldc, long czs,
    float escale, float* __restrict__ SM, float* __restrict__ SS,
    const float* __restrict__ Sf) {
  int z = blockIdx.z;
  int m0 = blockIdx.y * 128, n0 = blockIdx.x * 128;
  int k0 = 0, kend = Kh;
  const float* Sbase = nullptr;
  int head = 0;
  if (MODE == 0) {
    k0 = z * Kh;
    kend = k0 + Kh;
    C += (long)z * czs;
  } else if (MODE == 1) {
    if (blockIdx.x > blockIdx.y) return;  // fully-masked causal tile
    Ah += (long)z * TT * lda;
    Al += (long)z * TT * lda;
    Bh += (long)(z >> 2) * TT * ldb;
    Bl += (long)(z >> 2) * TT * ldb;
    C += (long)z * czs;
  } else {
    head = z >> 3;
    int ch = z & 7;
    int limit = (blockIdx.y + 1) * 128;  // causal k limit for this q-block
    k0 = ch * 128;
    if (k0 >= limit) return;
    kend = k0 + 128;
    Sbase = Sf + (long)head * TT * TT;
    Bh += (long)(head >> 2) * HDIM * ldb;
    Bl += (long)(head >> 2) * HDIM * ldb;
    C += (long)ch * czs + head * HDIM;
  }

  __shared__ __align__(16) char lds[32768];
  __shared__ float mrow[128], invrow[128];
  int tid = threadIdx.x, lane = tid & 63, wid = tid >> 6;
  int wm = (wid >> 1) * 64, wn = (wid & 1) * 64;
  int l15 = lane & 15, lg = lane >> 4;

  if (MODE == 2) {
    // per-row softmax stats from fused QK tile-stats
    if (tid < 128) {
      int q = m0 + tid;
      int nt = blockIdx.y + 1;
      float m = -1e30f;
      for (int t = 0; t < nt; ++t)
        m = fmaxf(m, SM[((long)head * 8 + t) * TT + q]);
      float den = 0.f;
      for (int t = 0; t < nt; ++t) {
        long so = ((long)head * 8 + t) * TT + q;
        den += SS[so] * __expf(SM[so] - m);
      }
      mrow[tid] = m;
      invrow[tid] = 1.f / den;
    }
  }

  f32x4 acc[4][4];
#pragma unroll
  for (int i = 0; i < 4; ++i)
#pragma unroll
    for (int j = 0; j < 4; ++j) acc[i][j] = {0.f, 0.f, 0.f, 0.f};

  for (int kt = k0; kt < kend; kt += 32) {
    __syncthreads();
    if (MODE == 2) {
      // stage Ph/Pl tiles from S: p = exp(s - m) * inv (causal-masked)
#pragma unroll
      for (int j = 0; j < 2; ++j) {
        int idx = tid + j * 256;
        int r = idx >> 2, c = idx & 3;
        int q = m0 + r;
        const float* sp = Sbase + (long)q * TT + kt + c * 8;
        float4 s0 = *(const float4*)sp;
        float4 s1 = *(const float4*)(sp + 4);
        float mq = mrow[r], iq = invrow[r];
        bf16x8 ph, pl;
        int kg0 = kt + c * 8;
#pragma unroll
        for (int u = 0; u < 8; ++u) {
          float s = (u < 4) ? ((const float*)&s0)[u] : ((const float*)&s1)[u - 4];
          float p = (kg0 + u <= q) ? __expf(s - mq) * iq : 0.f;
          unsigned short hh, ll;
          split2(p, hh, ll);
          ((unsigned short*)&ph)[u] = hh;
          ((unsigned short*)&pl)[u] = ll;
        }
        int off = r * 64 + ((c ^ swz4(r)) << 4);
        *(bf16x8*)(lds + off) = ph;
        *(bf16x8*)(lds + 8192 + off) = pl;
      }
    } else {
      stage_gll(Ah + (long)m0 * lda + kt, lda, lds, wid, lane);
      stage_gll(Al + (long)m0 * lda + kt, lda, lds + 8192, wid, lane);
    }
    stage_gll(Bh + (long)n0 * ldb + kt, ldb, lds + 16384, wid, lane);
    stage_gll(Bl + (long)n0 * ldb + kt, ldb, lds + 24576, wid, lane);
    __syncthreads();
    bf16x8 fah[4], fal[4], fbh[4], fbl[4];
    ld_frag(lds, wm, l15, lg, fah);
    ld_frag(lds + 16384, wn, l15, lg, fbh);
    mm16(fah, fbh, acc);
    ld_frag(lds + 24576, wn, l15, lg, fbl);
    mm16(fah, fbl, acc);
    ld_frag(lds + 8192, wm, l15, lg, fal);
    mm16(fal, fbh, acc);
  }

  if (MODE == 1) {
    int bx = blockIdx.x;
    bool diag = (bx == blockIdx.y);
    float vcap[4][4][4];
#pragma unroll
    for (int mi = 0; mi < 4; ++mi)
#pragma unroll
      for (int ni = 0; ni < 4; ++ni)
#pragma unroll
        for (int rr = 0; rr < 4; ++rr)
          vcap[mi][ni][rr] = tanh_cap30(acc[mi][ni][rr] * escale);
#pragma unroll
    for (int mi = 0; mi < 4; ++mi)
#pragma unroll
      for (int ni = 0; ni < 4; ++ni)
#pragma unroll
        for (int rr = 0; rr < 4; ++rr) {
          int ml = m0 + wm + mi * 16 + lg * 4 + rr;
          int col = n0 + wn + ni * 16 + l15;
          C[(long)ml * ldc + col] = vcap[mi][ni][rr];
        }
    __syncthreads();  // reuse lds for stats reduction
    float* wmx = (float*)lds;           // [2][128]
    float* wsm = (float*)(lds + 1024);  // [2][128]
    int ch = wid & 1;
#pragma unroll
    for (int mi = 0; mi < 4; ++mi)
#pragma unroll
      for (int rr = 0; rr < 4; ++rr) {
        int wr = wm + mi * 16 + lg * 4 + rr;
        int rowg = m0 + wr;
        float mx = -1e30f;
#pragma unroll
        for (int ni = 0; ni < 4; ++ni) {
          int colg = n0 + wn + ni * 16 + l15;
          if (!diag || colg <= rowg) mx = fmaxf(mx, vcap[mi][ni][rr]);
        }
#pragma unroll
        for (int mk = 1; mk <= 8; mk <<= 1)
          mx = fmaxf(mx, __shfl_xor(mx, mk, 64));
        if (l15 == 0) wmx[ch * 128 + wr] = mx;
      }
    __syncthreads();
#pragma unroll
    for (int mi = 0; mi < 4; ++mi)
#pragma unroll
      for (int rr = 0; rr < 4; ++rr) {
        int wr = wm + mi * 16 + lg * 4 + rr;
        int rowg = m0 + wr;
        float m2 = fmaxf(wmx[wr], wmx[128 + wr]);
        float s = 0.f;
#pragma unroll
        for (int ni = 0; ni < 4; ++ni) {
          int colg = n0 + wn + ni * 16 + l15;
          if (!diag || colg <= rowg) s += __expf(vcap[mi][ni][rr] - m2);
        }
#pragma unroll
        for (int mk = 1; mk <= 8; mk <<= 1) s += __shfl_xor(s, mk, 64);
        if (l15 == 0) wsm[ch * 128 + wr] = s;
      }
    __syncthreads();
    if (tid < 128) {
      float m2 = fmaxf(wmx[tid], wmx[128 + tid]);
      float s = wsm[tid] + wsm[128 + tid];
      long so = ((long)z * 8 + bx) * TT + m0 + tid;
      SM[so] = m2;
      SS[so] = s;
    }
    return;
  }

#pragma unroll
  for (int mi = 0; mi < 4; ++mi)
#pragma unroll
    for (int ni = 0; ni < 4; ++ni)
#pragma unroll
      for (int rr = 0; rr < 4; ++rr) {
        int ml = m0 + wm + mi * 16 + lg * 4 + rr;
        int col = n0 + wn + ni * 16 + l15;
        C[(long)ml * ldc + col] = acc[mi][ni][rr];
      }
}

// ---------------------------------------------------------------------------
// MoE bf16 GEMM: 128x128 tile, 256 threads, K-split 2 (proven optimum), gll A.
// z = expert*2 + kp. C = A[M][K](bf16 linear) @ B[K][N](f32, cast on stage)
// be computed in-kernel from cnt prefix (no scan dispatch).
// AMODE 1: A row gathered via tok; AMODE 2: A row = base+m (compact)
// EP 0: bf16 partial store at compacted rows (+ kp*pzs)
// EP 3: weighted bf16 scatter into slots_out (+ kp*pzs)
// ---------------------------------------------------------------------------
template <int AMODE, int EP>
__global__ __launch_bounds__(256) void gemm_k(
    const unsigned short* __restrict__ A, const float* __restrict__ Bf,
    unsigned short* __restrict__ Cb, int N, int K, int lda, int ldb, int ldc,
    long bzs, long pzs, const int* __restrict__ cnt,
    const int* __restrict__ tok, const int* __restrict__ slotp,
    const float* __restrict__ wtp, unsigned short* __restrict__ slots_out) {
  int z = blockIdx.z;
  int e = z >> 1, kp = z & 1;
  Bf += (long)e * bzs;
  int Me = cnt[e];
  int be = 0;
  for (int q = 0; q < e; ++q) be += cnt[q];
  int m0 = blockIdx.y * 128, n0 = blockIdx.x * 128;
  if (m0 >= Me) return;
  int Kc = K >> 1, kbeg = kp * Kc, klim = kbeg + Kc;

  __shared__ __align__(16) char lds[32768];
  const int BOFF = 16384;
  int tid = threadIdx.x, lane = tid & 63, wid = tid >> 6;
  int wm = (wid >> 1) * 64, wn = (wid & 1) * 64;
  int l15 = lane & 15, lg = lane >> 4;

  f32x4 acc[4][4];
#pragma unroll
  for (int i = 0; i < 4; ++i)
#pragma unroll
    for (int j = 0; j < 4; ++j) acc[i][j] = {0.f, 0.f, 0.f, 0.f};

  for (int kt = kbeg; kt < klim; kt += 64) {
    __syncthreads();
    // A tile [128][64] bf16 via gll: linear LDS dest + XOR-swizzled source.
    // chunk id MUST equal LDS slot = (wid*4+i)*64 + lane (rule #21).
#pragma unroll
    for (int i = 0; i < 4; ++i) {
      int idx = (wid * 4 + i) * 64 + lane;  // chunk id 0..1023 == slot
      int r = idx >> 3, c = idx & 7;
      int gm = m0 + r;
      long arow;
      if (AMODE == 1)
        arow = (gm < Me) ? (long)tok[e * TT + gm] : 0;
      else
        arow = (long)be + gm;
      int cs = c ^ swz8(r);
      const unsigned short* g = A + arow * (long)lda + kt + cs * 8;
      __builtin_amdgcn_global_load_lds(
          (const __attribute__((address_space(1))) unsigned int*)g,
          (__attribute__((address_space(3))) unsigned int*)(lds +
                                                           (wid * 4 + i) * 1024),
          16, 0, 0);
    }
    // B tile as [128 n][64 k]: coalesced column loads -> pack -> b128 write
#pragma unroll
    for (int i = 0; i < 4; ++i) {
      int gidx = tid + i * 256;
      int n = gidx & 127, kc = gidx >> 7;
      const float* src = Bf + (long)(kt + kc * 8) * ldb + n0 + n;
      bf16x8 v;
#pragma unroll
      for (int u = 0; u < 8; ++u)
        ((unsigned short*)&v)[u] = f2bf(src[(long)u * ldb]);
      *(bf16x8*)(lds + BOFF + n * 128 + ((kc ^ swz8(n)) << 4)) = v;
    }
    __syncthreads();
#pragma unroll
    for (int s = 0; s < 2; ++s) {
      bf16x8 af[4], bfr[4];
      int slotk = s * 4 + lg;
#pragma unroll
      for (int mi = 0; mi < 4; ++mi) {
        int row = wm + mi * 16 + l15;
        af[mi] =
            *(const bf16x8*)(lds + row * 128 + ((slotk ^ swz8(row)) << 4));
      }
#pragma unroll
      for (int ni = 0; ni < 4; ++ni) {
        int row = wn + ni * 16 + l15;
        bfr[ni] = *(const bf16x8*)(lds + BOFF + row * 128 +
                                   ((slotk ^ swz8(row)) << 4));
      }
      mm16(af, bfr, acc);
    }
  }
#pragma unroll
  for (int mi = 0; mi < 4; ++mi)
#pragma unroll
    for (int ni = 0; ni < 4; ++ni)
#pragma unroll
      for (int rr = 0; rr < 4; ++rr) {
        int ml = m0 + wm + mi * 16 + lg * 4 + rr;
        int col = n0 + wn + ni * 16 + l15;
        float val = acc[mi][ni][rr];
        if (ml < Me) {
          if (EP == 0) {
            Cb[(long)kp * pzs + (long)(be + ml) * ldc + col] = f2bf(val);
          } else {
            int t = tok[e * TT + ml];
            int s = slotp[e * TT + ml];
            float w = wtp[e * TT + ml];
            slots_out[(long)kp * pzs + ((long)s * TT + t) * DD + col] =
                f2bf(val * w);
          }
        }
      }
}

// ---------------------------------------------------------------------------
// prep: blocks [0,2560) = transpose+split of both attention weights
//       (pre-swizzled); blocks [2560, 2560+TT) = pre-attn rmsnorm+split2.
//       block 0 also zeroes cnt.
__global__ __launch_bounds__(256) void prep_k(
    const float* __restrict__ Wq, unsigned short* __restrict__ Thq,
    unsigned short* __restrict__ Tlq, const float* __restrict__ Wo,
    unsigned short* __restrict__ Tho, unsigned short* __restrict__ Tlo,
    const float* __restrict__ x, const float* __restrict__ wpre,
    unsigned short* __restrict__ h1h, unsigned short* __restrict__ h1l,
    int* __restrict__ cnt) {
  __shared__ float lds[64 * 65];
  int b = blockIdx.x, tid = threadIdx.x;
  if (b == 0 && tid < NE) cnt[tid] = 0;
  if (b >= 2560) {  // ---- rmsnorm path ----
    int t = b - 2560;
    const float* xr = x + (long)t * DD;
    float xv[8];
    float ss = 0.f;
#pragma unroll
    for (int i = 0; i < 8; ++i) {
      float v = xr[tid + i * 256];
      xv[i] = v;
      ss += v * v;
    }
    ss = wave_sum(ss);
    if ((tid & 63) == 0) lds[tid >> 6] = ss;
    __syncthreads();
    float r = rsqrtf((lds[0] + lds[1] + lds[2] + lds[3]) * (1.f / DD) + EPSF);
#pragma unroll
    for (int i = 0; i < 8; ++i) {
      int d = tid + i * 256;
      int ds = swzoff(t, d);
      split2(xv[i] * r * wpre[d], h1h[(long)t * DD + ds],
             h1l[(long)t * DD + ds]);
    }
    return;
  }
  // ---- weight transpose+split path ----
  const float* W;
  unsigned short *Th, *Tl;
  int K = DD, N, bx, by;
  if (b < 1536) {  // w_qkv: [2048][3072]
    W = Wq; Th = Thq; Tl = Tlq; N = 3072; bx = b % 48; by = b / 48;
  } else {  // w_o: [2048][2048]
    int b2 = b - 1536;
    W = Wo; Th = Tho; Tl = Tlo; N = DD; bx = b2 % 32; by = b2 / 32;
  }
  int n0 = bx * 64, k0 = by * 64;
#pragma unroll
  for (int i = 0; i < 4; ++i) {
    int idx = tid + i * 256;  // 1024 float4s = 64k x 64n
    int kr = idx >> 4, cg = idx & 15;
    float4 v = *(const float4*)(W + (long)(k0 + kr) * N + n0 + cg * 4);
    float* p = &lds[kr * 65 + cg * 4];
    p[0] = v.x; p[1] = v.y; p[2] = v.z; p[3] = v.w;
  }
  __syncthreads();
#pragma unroll
  for (int i = 0; i < 2; ++i) {
    int idx = tid + i * 256;  // 512 out-chunks of 8 k
    int n = idx >> 3, kc = idx & 7;
    bf16x8 h8, l8;
#pragma unroll
    for (int u = 0; u < 8; ++u) {
      unsigned short hh, ll;
      split2(lds[(kc * 8 + u) * 65 + n], hh, ll);
      ((unsigned short*)&h8)[u] = hh;
      ((unsigned short*)&l8)[u] = ll;
    }
    int row = n0 + n;
    long o = (long)row * K + swzoff(row, k0 + kc * 8);
    *(bf16x8*)(Th + o) = h8;
    *(bf16x8*)(Tl + o) = l8;
  }
}

// fused: blocks 0..TT-1 = q/k RoPE+split2; blocks TT.. = V transpose+split2
__global__ __launch_bounds__(256) void ropevt_k(
    const int* __restrict__ pos, const float* __restrict__ qp,
    unsigned short* __restrict__ qh, unsigned short* __restrict__ ql,
    unsigned short* __restrict__ kh, unsigned short* __restrict__ kl,
    unsigned short* __restrict__ Vh, unsigned short* __restrict__ Vl) {
  __shared__ __align__(16) float smem[64 * 129];
  int b = blockIdx.x, tid = threadIdx.x;
  const long PS = (long)TT * 3072;
  if (b < TT) {  // ---- RoPE on q,k ----
    float* cs = smem;
    float* sn = smem + 64;
    int t = b;
    float pf = (float)pos[t];
    if (tid < 64) {
      float inv = exp2f(-(float)tid * 0.20762050593046015f);  // log2(1e4)/64
      float f = pf * inv;
      cs[tid] = cosf(f);
      sn[tid] = sinf(f);
    }
    __syncthreads();
    const float* row = qp + (long)t * 3072;
#pragma unroll
    for (int i = 0; i < 4; ++i) {
      int idx = tid + i * 256;  // q: 16 heads x 64
      int h = idx >> 6, j = idx & 63;
      float x1 = 0.f, x2 = 0.f;
#pragma unroll
      for (int p = 0; p < NP; ++p) {
        x1 += row[p * PS + h * HDIM + j];
        x2 += row[p * PS + h * HDIM + 64 + j];
      }
      float c = cs[j], s = sn[j];
      long base = ((long)h * TT + t) * HDIM;
      split2(x1 * c - x2 * s, qh[base + swzoff(t, j)], ql[base + swzoff(t, j)]);
      split2(x2 * c + x1 * s, qh[base + swzoff(t, 64 + j)],
             ql[base + swzoff(t, 64 + j)]);
    }
    {
      int k2 = tid >> 6, j = tid & 63;  // k: 4 heads x 64
      float x1 = 0.f, x2 = 0.f;
#pragma unroll
      for (int p = 0; p < NP; ++p) {
        x1 += row[p * PS + 2048 + k2 * HDIM + j];
        x2 += row[p * PS + 2048 + k2 * HDIM + 64 + j];
      }
      float c = cs[j], s = sn[j];
      long base = ((long)k2 * TT + t) * HDIM;
      split2(x1 * c - x2 * s, kh[base + swzoff(t, j)], kl[base + swzoff(t, j)]);
      split2(x2 * c + x1 * s, kh[base + swzoff(t, 64 + j)],
             kl[base + swzoff(t, 64 + j)]);
    }
  } else {  // ---- V transpose ----
    int bb = b - TT;
    int tb = bb & 7, kv = bb >> 3;
    int t0 = tb * 128;
#pragma unroll
    for (int dh = 0; dh < 2; ++dh) {
      if (dh) __syncthreads();
#pragma unroll
      for (int i = 0; i < 8; ++i) {
        int fidx = tid + i * 256;  // 2048 float4s = 128t x 64d
        int t = fidx >> 4, dq = fidx & 15;
        long gi = (long)(t0 + t) * 3072 + 2560 + kv * HDIM + dh * 64 + dq * 4;
        float4 a = *(const float4*)(qp + gi);
#pragma unroll
        for (int p = 1; p < NP; ++p) {
          float4 bb4 = *(const float4*)(qp + p * PS + gi);
          a.x += bb4.x; a.y += bb4.y; a.z += bb4.z; a.w += bb4.w;
        }
        smem[(dq * 4 + 0) * 129 + t] = a.x;
        smem[(dq * 4 + 1) * 129 + t] = a.y;
        smem[(dq * 4 + 2) * 129 + t] = a.z;
        smem[(dq * 4 + 3) * 129 + t] = a.w;
      }
      __syncthreads();
#pragma unroll
      for (int i = 0; i < 4; ++i) {
        int cidx = tid + i * 256;  // 1024 chunks = 64d x 16tc
        int d = cidx >> 4, tc = cidx & 15;
        bf16x8 h8, l8;
#pragma unroll
        for (int u = 0; u < 8; ++u) {
          unsigned short hh, ll;
          split2(smem[d * 129 + tc * 8 + u], hh, ll);
          ((unsigned short*)&h8)[u] = hh;
          ((unsigned short*)&l8)[u] = ll;
        }
        int rowd = dh * 64 + d;
        long o = ((long)kv * HDIM + rowd) * TT + swzoff(rowd, t0 + tc * 8);
        *(bf16x8*)(Vh + o) = h8;
        *(bf16x8*)(Vl + o) = l8;
      }
    }
  }
}

// sum valid PV chunks, split2 -> ob (pre-swizzled)
__global__ __launch_bounds__(256) void obreduce_k(const float* __restrict__ obp,
                                                  unsigned short* __restrict__ oh,
                                                  unsigned short* __restrict__ ol) {
  int m = blockIdx.x, tid = threadIdx.x;
  int nv = (m >> 7) + 1;  // 128-k chunks with k0 <= m
#pragma unroll
  for (int i = 0; i < 8; ++i) {
    int d = tid + i * 256;
    float s = 0.f;
    for (int c = 0; c < nv; ++c) s += obp[(long)c * TT * DD + (long)m * DD + d];
    int ds = swzoff(m, d);
    split2(s, oh[(long)m * DD + ds], ol[(long)m * DD + ds]);
  }
}

// post-attn residual + two rmsnorms + h2 bf16 + FUSED gate top-2 routing
__global__ __launch_bounds__(256) void post_attn_gate_k(
    const float* __restrict__ ap, const float* __restrict__ hidden,
    const float* __restrict__ w_post, const float* __restrict__ w_pre2,
    const float* __restrict__ wg, float* __restrict__ resid1,
    unsigned short* __restrict__ h2b, int* cnt, int* tok, int* slotp,
    float* wtp) {
  __shared__ float red[4];
  __shared__ float red8[4][8];
  int t = blockIdx.x, tid = threadIdx.x;
  const long PS = (long)TT * DD;
  float av[8];
  float ss = 0.f;
#pragma unroll
  for (int i = 0; i < 8; ++i) {
    long o = (long)t * DD + tid + i * 256;
    float v = 0.f;
#pragma unroll
    for (int p = 0; p < NP; ++p) v += ap[p * PS + o];
    av[i] = v;
    ss += v * v;
  }
  ss = wave_sum(ss);
  if ((tid & 63) == 0) red[tid >> 6] = ss;
  __syncthreads();
  float r1 = rsqrtf((red[0] + red[1] + red[2] + red[3]) * (1.f / DD) + EPSF);
  __syncthreads();
  float rv[8];
  float ss2 = 0.f;
#pragma unroll
  for (int i = 0; i < 8; ++i) {
    int d = tid + i * 256;
    float v = hidden[(long)t * DD + d] + av[i] * r1 * w_post[d];
    rv[i] = v;
    resid1[(long)t * DD + d] = v;
    ss2 += v * v;
  }
  ss2 = wave_sum(ss2);
  if ((tid & 63) == 0) red[tid >> 6] = ss2;
  __syncthreads();
  float r2 = rsqrtf((red[0] + red[1] + red[2] + red[3]) * (1.f / DD) + EPSF);
  float a[8] = {0, 0, 0, 0, 0, 0, 0, 0};
#pragma unroll
  for (int i = 0; i < 8; ++i) {
    int d = tid + i * 256;
    float hv = rv[i] * r2 * w_pre2[d];
    h2b[(long)t * DD + d] = f2bf(hv);  // linear (MoE gll source-swizzles)
    const float* wr = wg + d * 8;
#pragma unroll
    for (int e = 0; e < 8; ++e) a[e] += hv * wr[e];
  }
#pragma unroll
  for (int e = 0; e < 8; ++e) a[e] = wave_sum(a[e]);
  if ((tid & 63) == 0) {
#pragma unroll
    for (int e = 0; e < 8; ++e) red8[tid >> 6][e] = a[e];
  }
  __syncthreads();
  if (tid == 0) {
    float l[8], p[8];
    float m = -1e30f;
    for (int e = 0; e < 8; ++e) {
      float v = red8[0][e] + red8[1][e] + red8[2][e] + red8[3][e];
      v = 30.f * tanhf(v * (1.f / 30.f));  // exact: top-2 flip-sensitive
      l[e] = v;
      m = fmaxf(m, v);
    }
    float s = 0.f;
    for (int e = 0; e < 8; ++e) { p[e] = expf(l[e] - m); s += p[e]; }
    for (int e = 0; e < 8; ++e) p[e] /= s;
    int i1 = 0;
    for (int e = 1; e < 8; ++e) if (p[e] > p[i1]) i1 = e;
    int i2 = (i1 == 0) ? 1 : 0;
    for (int e = 0; e < 8; ++e) if (e != i1 && p[e] > p[i2]) i2 = e;
    int q1 = atomicAdd(&cnt[i1], 1);
    tok[i1 * TT + q1] = t; slotp[i1 * TT + q1] = 0; wtp[i1 * TT + q1] = p[i1];
    int q2 = atomicAdd(&cnt[i2], 1);
    tok[i2 * TT + q2] = t; slotp[i2 * TT + q2] = 1; wtp[i2 * TT + q2] = p[i2];
  }
}

// act over sum of 2 bf16 K-split gu partials (fast gelu)
__global__ __launch_bounds__(256) void act_k(const unsigned short* __restrict__ gu,
                                             unsigned short* __restrict__ actb) {
  long a = blockIdx.x;
  const long PS = (long)2 * TT * 2 * NI;
  const unsigned short* g0 = gu + a * (2 * NI);
  const unsigned short* g1 = g0 + PS;
  for (int i = threadIdx.x; i < NI; i += 256) {
    float gg = bf2f(g0[i]) + bf2f(g1[i]);
    float uu = bf2f(g0[i + NI]) + bf2f(g1[i + NI]);
    float y = 0.7978845608028654f * (gg + 0.044715f * gg * gg * gg);
    float ey = __expf(2.f * y);
    float th = 1.f - 2.f / (ey + 1.f);
    actb[a * NI + i] = f2bf(0.5f * gg * (1.f + th) * uu);
  }
}

// final: sum 4 bf16 slot planes (2 kp x 2 slots) + rmsnorm + resid
__global__ __launch_bounds__(256) void final_k(
    const float* __restrict__ resid1, const unsigned short* __restrict__ slots,
    const float* __restrict__ w2, float* __restrict__ out) {
  __shared__ float red[4];
  int t = blockIdx.x, tid = threadIdx.x;
  const long PL = (long)TT * DD;
  float mv[8];
  float ss = 0.f;
#pragma unroll
  for (int i = 0; i < 8; ++i) {
    long o = (long)t * DD + tid + i * 256;
    float v = bf2f(slots[o]) + bf2f(slots[PL + o]) + bf2f(slots[2 * PL + o]) +
              bf2f(slots[3 * PL + o]);
    mv[i] = v;
    ss += v * v;
  }
  ss = wave_sum(ss);
  if ((tid & 63) == 0) red[tid >> 6] = ss;
  __syncthreads();
  float r = rsqrtf((red[0] + red[1] + red[2] + red[3]) * (1.f / DD) + EPSF);
#pragma unroll
  for (int i = 0; i < 8; ++i) {
    int d = tid + i * 256;
    out[(long)t * DD + d] = resid1[(long)t * DD + d] + mv[i] * r * w2[d];
  }
}

__global__ void sentinel_k(float* out) { out[threadIdx.x] = 12345.0f; }

// ---------------------------------------------------------------------------
extern "C" void kernel_launch(void* const* d_in, const int* in_sizes, int n_in,
                              void* d_out, int out_size, void* d_ws,
                              size_t ws_size, hipStream_t stream) {
  const int* pos = (const int*)d_in[0];
  const float* hidden = (const float*)d_in[1];
  const float* w_qkv = (const float*)d_in[2];
  const float* w_o = (const float*)d_in[3];
  const float* w_gate = (const float*)d_in[4];
  const float* w_gu = (const float*)d_in[5];
  const float* w_down = (const float*)d_in[6];
  const float* w_pre_attn = (const float*)d_in[7];
  const float* w_post_attn = (const float*)d_in[8];
  const float* w_pre_moe = (const float*)d_in[9];
  const float* w_post_moe = (const float*)d_in[10];
  float* out = (float*)d_out;

  char* ws = (char*)d_ws;
  size_t off = 0;
  auto alloc = [&](size_t bytes) {
    char* p = ws + off;
    off += (bytes + 255) & ~(size_t)255;
    return p;
  };
  typedef unsigned short u16;
  u16* h1h = (u16*)alloc((size_t)TT * DD * 2);
  u16* h1l = (u16*)alloc((size_t)TT * DD * 2);
  u16* wqkvTh = (u16*)alloc((size_t)3072 * DD * 2);
  u16* wqkvTl = (u16*)alloc((size_t)3072 * DD * 2);
  float* qkvp = (float*)alloc((size_t)NP * TT * 3072 * 4);
  u16* qh_ = (u16*)alloc((size_t)NH * TT * HDIM * 2);
  u16* ql_ = (u16*)alloc((size_t)NH * TT * HDIM * 2);
  u16* kh_ = (u16*)alloc((size_t)NKV * TT * HDIM * 2);
  u16* kl_ = (u16*)alloc((size_t)NKV * TT * HDIM * 2);
  u16* vth = (u16*)alloc((size_t)NKV * HDIM * TT * 2);
  u16* vtl = (u16*)alloc((size_t)NKV * HDIM * TT * 2);
  float* S = (float*)alloc((size_t)NH * TT * TT * 4);
  float* SMb = (float*)alloc((size_t)NH * 8 * TT * 4);
  float* SSb = (float*)alloc((size_t)NH * 8 * TT * 4);
  float* obp = (float*)alloc((size_t)8 * TT * DD * 4);
  u16* obh = (u16*)alloc((size_t)TT * DD * 2);
  u16* obl = (u16*)alloc((size_t)TT * DD * 2);
  u16* woTh = (u16*)alloc((size_t)DD * DD * 2);
  u16* woTl = (u16*)alloc((size_t)DD * DD * 2);
  float* attnp = (float*)alloc((size_t)NP * TT * DD * 4);
  float* resid1 = (float*)alloc((size_t)TT * DD * 4);
  u16* h2b = (u16*)alloc((size_t)TT * DD * 2);
  int* cnt = (int*)alloc(NE * 4);
  int* tok = (int*)alloc((size_t)NE * TT * 4);
  int* slotp = (int*)alloc((size_t)NE * TT * 4);
  float* wtp = (float*)alloc((size_t)NE * TT * 4);
  u16* gu = (u16*)alloc((size_t)2 * 2 * TT * 2 * NI * 2);  // [kp2][2TT][2NI]
  u16* actb = (u16*)alloc((size_t)2 * TT * NI * 2);
  u16* slots = (u16*)alloc((size_t)2 * 2 * TT * DD * 2);   // [kp2][2][TT][DD]

  if (off > ws_size) {  // distinctive failure signal, no OOB writes
    sentinel_k<<<1, 256, 0, stream>>>(out);
    return;
  }

  dim3 blk(256);

  // weights transpose+split + pre-attn rmsnorm + cnt zeroing (one dispatch)
  prep_k<<<2560 + TT, blk, 0, stream>>>(w_qkv, wqkvTh, wqkvTl, w_o, woTh,
                                        woTl, hidden, w_pre_attn, h1h, h1l,
                                        cnt);

  // qkv partials (K split in NP)
  pgemm3_k<0><<<dim3(3072 / 128, TT / 128, NP), blk, 0, stream>>>(
      h1h, h1l, wqkvTh, wqkvTl, qkvp, DD / NP, DD, DD, 3072, (long)TT * 3072,
      0.f, nullptr, nullptr, nullptr);

  ropevt_k<<<TT + 32, blk, 0, stream>>>(pos, qkvp, qh_, ql_, kh_, kl_, vth,
                                        vtl);

  // S = cap_tanh(scale * Q K^T), causal skip, + fused softmax tile-stats
  pgemm3_k<1><<<dim3(TT / 128, TT / 128, NH), blk, 0, stream>>>(
      qh_, ql_, kh_, kl_, S, HDIM, HDIM, HDIM, TT, (long)TT * TT,
      0.08838834764831845f, SMb, SSb, nullptr);

  // O partials: softmax fused into PV A-staging; 128-k causal chunks
  pgemm3_k<2><<<dim3(1, TT / 128, NH * 8), blk, 0, stream>>>(
      nullptr, nullptr, vth, vtl, obp, 128, TT, TT, DD, (long)TT * DD, 0.f,
      SMb, SSb, S);
  obreduce_k<<<TT, blk, 0, stream>>>(obp, obh, obl);

  // attn partials = O @ w_o (K split in NP)
  pgemm3_k<0><<<dim3(DD / 128, TT / 128, NP), blk, 0, stream>>>(
      obh, obl, woTh, woTl, attnp, DD / NP, DD, DD, DD, (long)TT * DD, 0.f,
      nullptr, nullptr, nullptr);

  post_attn_gate_k<<<TT, blk, 0, stream>>>(attnp, hidden, w_post_attn,
                                           w_pre_moe, w_gate, resid1, h2b, cnt,
                                           tok, slotp, wtp);

  // gu partials [2][2TT][2NI] bf16 = h2[tok] @ w_gate_up[e]  (K-split 2)
  gemm_k<1, 0><<<dim3(2 * NI / 128, TT / 128, NE * 2), blk, 0, stream>>>(
      h2b, w_gu, gu, 2 * NI, DD, DD, 2 * NI, 2 * NI, (long)DD * 2 * NI,
      (long)2 * TT * 2 * NI, cnt, tok, nullptr, nullptr, nullptr);

  act_k<<<2 * TT, blk, 0, stream>>>(gu, actb);

  // down partials -> slots [2][2][TT][DD] bf16  (K-split 2)
  gemm_k<2, 3><<<dim3(DD / 128, TT / 128, NE * 2), blk, 0, stream>>>(
      actb, w_down, nullptr, DD, NI, NI, DD, DD, (long)NI * DD,
      (long)2 * TT * DD, cnt, tok, slotp, wtp, slots);

  final_k<<<TT, blk, 0, stream>>>(resid1, slots, w_post_moe, out);
}